// Round 10
// baseline (155.761 us; speedup 1.0000x reference)
//
#include <hip/hip_runtime.h>
#include <math.h>

// Sizes (fixed by the problem)
#define B_SZ 8
#define T_LEN 4096
#define D_IN 128
#define D_OUT 128
#define N_ST 256
#define BT (B_SZ * T_LEN)        // 32768
#define CHUNK 64                 // scan chunk length
#define NCHUNK (T_LEN / CHUNK)   // 64 chunks per sequence
#define NBLK (B_SZ * NCHUNK)     // 512 chunk-blocks

typedef __attribute__((ext_vector_type(8))) short short8;
typedef __attribute__((ext_vector_type(4))) float f32x4;
typedef unsigned int uint;
typedef unsigned short ushort;

static __device__ __forceinline__ short f2bf(float f) {
  union { float f; uint u; } v; v.f = f;
  uint r = v.u + 0x7FFFu + ((v.u >> 16) & 1u);  // round-to-nearest-even
  return (short)(r >> 16);
}
static __device__ __forceinline__ float bf2f(uint h) {
  union { uint u; float f; } v; v.u = h << 16;
  return v.f;
}
static __device__ __forceinline__ uint pack2(float a, float b) {
  return (uint)(ushort)f2bf(a) | ((uint)(ushort)f2bf(b) << 16);
}

// ---------------------------------------------------------------------------
// k0_setup: R7/R9 VERBATIM (validated).
// ---------------------------------------------------------------------------
__global__ __launch_bounds__(256) void k0_setup(
    const float* __restrict__ nu_log, const float* __restrict__ theta_log,
    const float* __restrict__ gamma_log,
    const float* __restrict__ B_re, const float* __restrict__ B_im,
    const float* __restrict__ C_re, const float* __restrict__ C_im,
    const float* __restrict__ Dm,
    short* __restrict__ Wf1, short* __restrict__ Wf2,
    float2* __restrict__ lampow2) {
  int blk = blockIdx.x;
  if (blk < 320) {
    int idx = blk * 256 + threadIdx.x;
    if (idx < 16 * 512 * 8) {
      int j = idx & 7, col = (idx >> 3) & 511, kg = idx >> 12;
      int k = kg * 8 + j;
      int n = col >> 1, ri = col & 1;
      float g = expf(gamma_log[n]);
      float v = g * (ri ? B_im[n * D_IN + k] : B_re[n * D_IN + k]);
      Wf1[idx] = f2bf(v);
    }
    if (idx < 80 * 128 * 8) {
      int j = idx & 7, d = (idx >> 3) & 127, kg = idx >> 10;
      int k = kg * 8 + j;
      float v;
      if (k < 512) {
        int n = k >> 1;
        v = (k & 1) ? -C_im[d * N_ST + n] : C_re[d * N_ST + n];
      } else {
        v = Dm[d * D_IN + (k - 512)];
      }
      Wf2[idx] = f2bf(v);
    }
  } else {
    int j = blk - 320;  // 0..64
    int n = threadIdx.x;
    float e_nu = expf(nu_log[n]);
    float phase = expf(theta_log[n]);
    float r = expf(-(float)j * e_nu);
    float a = (float)j * phase;
    float2 v; v.x = r * cosf(a); v.y = r * sinf(a);
    lampow2[j * N_ST + n] = v;
  }
}

// ---------------------------------------------------------------------------
// kA: R2/R7/R9 VERBATIM (validated). Fused GEMM1 (bf16 MFMA) + local chunk
// scan -> global bf16 states + chunk carry E.
// ---------------------------------------------------------------------------
__global__ __launch_bounds__(256, 2) void kA(
    const float* __restrict__ x, const short* __restrict__ Wf1,
    const float2* __restrict__ lampow2,
    uint* __restrict__ states, float2* __restrict__ E) {
  __shared__ short bu[64 * 520];   // row-major, +8 pad per row

  int bc = blockIdx.x;
  size_t row0 = (size_t)bc * CHUNK;
  int tid = threadIdx.x;
  int lane = tid & 63, w = tid >> 6;
  int m = lane & 15, q = lane >> 4;

  f32x4 acc[32];
#pragma unroll
  for (int ct = 0; ct < 32; ++ct) acc[ct] = (f32x4){0.f, 0.f, 0.f, 0.f};

  const float* xrow = x + (row0 + 16 * w + m) * D_IN;

  for (int ks = 0; ks < 4; ++ks) {
    float4 xa = *(const float4*)(xrow + 32 * ks + 8 * q);
    float4 xb = *(const float4*)(xrow + 32 * ks + 8 * q + 4);
    short8 af;
    af[0] = f2bf(xa.x); af[1] = f2bf(xa.y); af[2] = f2bf(xa.z); af[3] = f2bf(xa.w);
    af[4] = f2bf(xb.x); af[5] = f2bf(xb.y); af[6] = f2bf(xb.z); af[7] = f2bf(xb.w);
    const short* wbase = Wf1 + ((size_t)(4 * ks + q) * 512 + m) * 8;
#pragma unroll
    for (int ct = 0; ct < 32; ++ct) {
      short8 bf = *(const short8*)(wbase + 16 * ct * 8);
      acc[ct] = __builtin_amdgcn_mfma_f32_16x16x32_bf16(af, bf, acc[ct], 0, 0, 0);
    }
  }

  // write Bu tile to LDS (bf16). C-layout: row=4q+r, col=m within 16x16 tile.
#pragma unroll
  for (int ct = 0; ct < 32; ++ct) {
#pragma unroll
    for (int r = 0; r < 4; ++r) {
      bu[(16 * w + 4 * q + r) * 520 + 16 * ct + m] = f2bf(acc[ct][r]);
    }
  }
  __syncthreads();

  // scan: thread n owns state n
  int n = tid;
  float2 lam = lampow2[N_ST + n];  // lam^1
  float sre = 0.f, sim = 0.f;
  uint* sg = states + row0 * N_ST + n;
  for (int j = 0; j < CHUNK; ++j) {
    uint p = ((const uint*)(bu + j * 520))[n];
    float br = bf2f(p & 0xffffu), bi = bf2f(p >> 16);
    float nr = fmaf(lam.x, sre, fmaf(-lam.y, sim, br));
    float ni = fmaf(lam.x, sim, fmaf(lam.y, sre, bi));
    sre = nr; sim = ni;
    sg[(size_t)j * N_ST] = pack2(sre, sim);
  }
  float2 e; e.x = sre; e.y = sim;
  E[bc * N_ST + n] = e;
}

// ---------------------------------------------------------------------------
// kC: R9 kC with VECTORIZED memory pipeline.
//  - carry: R9-verbatim per-n recurrence -> LDS Pl[256] (2 KB)
//  - phase 1a': thread (n4=tid&63, rblk=tid>>6); 16 iters of uint4 states
//    load (4 states), fix-up x4, one b128 LDS store to granule g=n4 at the
//    SAME swizzled address R9 wrote (bijective re-assignment, same values).
//  - phase 1b / phase 2: R9 verbatim.
// ---------------------------------------------------------------------------
__global__ __launch_bounds__(256, 2) void kC(
    const float* __restrict__ x, const uint* __restrict__ states,
    const float2* __restrict__ E, const float2* __restrict__ lampow2,
    const short* __restrict__ Wf2, float* __restrict__ y) {
  __shared__ short As[64 * 640];   // 80 KB
  __shared__ float2 Pl[N_ST];      // 2 KB

  int bc = blockIdx.x;
  size_t row0 = (size_t)bc * CHUNK;
  int tid = threadIdx.x;
  int n = tid;

  // ---- in-kernel carry (R9 verbatim chain) -> Pl ----
  {
    float pre = 0.f, pim = 0.f;
    float2 lamL = lampow2[CHUNK * N_ST + n];  // lam^64
    int c = bc & (NCHUNK - 1), b = bc >> 6;
    for (int j = 0; j < c; ++j) {
      float2 e = E[(size_t)((b << 6) + j) * N_ST + n];
      float nre = fmaf(lamL.x, pre, fmaf(-lamL.y, pim, e.x));
      float nim = fmaf(lamL.x, pim, fmaf(lamL.y, pre, e.y));
      pre = nre; pim = nim;
    }
    float2 pv; pv.x = pre; pv.y = pim;
    Pl[n] = pv;
  }

  // phase 1b: x -> LDS bf16 (cols 512..639) (R9 verbatim; disjoint As cols)
  {
    int kxp = tid & 63, r0 = tid >> 6;
    int k = 512 + 2 * kxp;
    int g = k >> 3, koff = k & 7;
    for (int rr = 0; rr < 16; ++rr) {
      int row = r0 * 16 + rr;
      float2 xv = *(const float2*)(x + (row0 + row) * D_IN + 2 * kxp);
      int gp = (g & ~7) | ((g + row) & 7);
      *(uint*)(As + row * 640 + gp * 8 + koff) = pack2(xv.x, xv.y);
    }
  }
  __syncthreads();  // Pl visible to all

  // phase 1a': vectorized states fix-up -> As cols 0..511
  {
    int n4 = tid & 63, rblk = tid >> 6;
    float2 p0 = Pl[4 * n4 + 0];
    float2 p1 = Pl[4 * n4 + 1];
    float2 p2 = Pl[4 * n4 + 2];
    float2 p3 = Pl[4 * n4 + 3];
#pragma unroll
    for (int rr = 0; rr < 16; ++rr) {
      int row = rblk * 16 + rr;
      uint4 sp = *(const uint4*)(states + ((row0 + row) * N_ST + 4 * n4));
      float4 lpa = *(const float4*)(lampow2 + ((size_t)(row + 1) * N_ST + 4 * n4));
      float4 lpb = *(const float4*)(lampow2 + ((size_t)(row + 1) * N_ST + 4 * n4 + 2));
      uint4 outv;
      {
        float sr = bf2f(sp.x & 0xffffu) + lpa.x * p0.x - lpa.y * p0.y;
        float si = bf2f(sp.x >> 16)     + lpa.x * p0.y + lpa.y * p0.x;
        outv.x = pack2(sr, si);
      }
      {
        float sr = bf2f(sp.y & 0xffffu) + lpa.z * p1.x - lpa.w * p1.y;
        float si = bf2f(sp.y >> 16)     + lpa.z * p1.y + lpa.w * p1.x;
        outv.y = pack2(sr, si);
      }
      {
        float sr = bf2f(sp.z & 0xffffu) + lpb.x * p2.x - lpb.y * p2.y;
        float si = bf2f(sp.z >> 16)     + lpb.x * p2.y + lpb.y * p2.x;
        outv.z = pack2(sr, si);
      }
      {
        float sr = bf2f(sp.w & 0xffffu) + lpb.z * p3.x - lpb.w * p3.y;
        float si = bf2f(sp.w >> 16)     + lpb.z * p3.y + lpb.w * p3.x;
        outv.w = pack2(sr, si);
      }
      int g = n4;
      int gp = (g & ~7) | ((g + row) & 7);
      *(uint4*)(As + row * 640 + gp * 8) = outv;
    }
  }
  __syncthreads();

  // phase 2: MFMA (R9 verbatim). wave w -> rows 16w..16w+15; 8 col-tiles.
  int lane = tid & 63, w = tid >> 6;
  int m = lane & 15, q = lane >> 4;
  int arow = 16 * w + m;

  f32x4 acc[8];
#pragma unroll
  for (int ct = 0; ct < 8; ++ct) acc[ct] = (f32x4){0.f, 0.f, 0.f, 0.f};

  for (int ks = 0; ks < 20; ++ks) {
    int g = 4 * ks + q;
    int gp = (g & ~7) | ((g + arow) & 7);
    short8 af = *(const short8*)(As + arow * 640 + gp * 8);
    const short* wbase = Wf2 + ((size_t)g * 128 + m) * 8;
#pragma unroll
    for (int ct = 0; ct < 8; ++ct) {
      short8 bf = *(const short8*)(wbase + 16 * ct * 8);
      acc[ct] = __builtin_amdgcn_mfma_f32_16x16x32_bf16(af, bf, acc[ct], 0, 0, 0);
    }
  }

#pragma unroll
  for (int ct = 0; ct < 8; ++ct) {
#pragma unroll
    for (int r = 0; r < 4; ++r) {
      y[(row0 + 16 * w + 4 * q + r) * D_OUT + 16 * ct + m] = acc[ct][r];
    }
  }
}

// ---------------------------------------------------------------------------
extern "C" void kernel_launch(void* const* d_in, const int* in_sizes, int n_in,
                              void* d_out, int out_size, void* d_ws, size_t ws_size,
                              hipStream_t stream) {
  const float* x         = (const float*)d_in[0];
  const float* nu_log    = (const float*)d_in[1];
  const float* theta_log = (const float*)d_in[2];
  const float* gamma_log = (const float*)d_in[3];
  const float* B_re      = (const float*)d_in[4];
  const float* B_im      = (const float*)d_in[5];
  const float* C_re      = (const float*)d_in[6];
  const float* C_im      = (const float*)d_in[7];
  const float* Dm        = (const float*)d_in[8];
  float* y = (float*)d_out;

  char* wp = (char*)d_ws;
  float2* lampow2 = (float2*)wp; wp += (size_t)(CHUNK + 1) * N_ST * sizeof(float2);
  short*  Wf1     = (short*)wp;  wp += (size_t)16 * 512 * 8 * sizeof(short);
  short*  Wf2     = (short*)wp;  wp += (size_t)80 * 128 * 8 * sizeof(short);
  float2* E       = (float2*)wp; wp += (size_t)NBLK * N_ST * sizeof(float2);
  uint*   states  = (uint*)wp;   wp += (size_t)BT * N_ST * sizeof(uint);

  hipLaunchKernelGGL(k0_setup, dim3(385), dim3(256), 0, stream,
                     nu_log, theta_log, gamma_log, B_re, B_im, C_re, C_im, Dm,
                     Wf1, Wf2, lampow2);
  hipLaunchKernelGGL(kA, dim3(NBLK), dim3(256), 0, stream,
                     x, Wf1, lampow2, states, E);
  hipLaunchKernelGGL(kC, dim3(NBLK), dim3(256), 0, stream,
                     x, states, E, lampow2, Wf2, y);
}

// Round 11
// 142.250 us; speedup vs baseline: 1.0950x; 1.0950x over previous
//
#include <hip/hip_runtime.h>
#include <math.h>

// Sizes (fixed by the problem)
#define B_SZ 8
#define T_LEN 4096
#define D_IN 128
#define D_OUT 128
#define N_ST 256
#define BT (B_SZ * T_LEN)        // 32768
#define CHUNK 64                 // scan chunk length
#define NCHUNK (T_LEN / CHUNK)   // 64 chunks per sequence
#define NBLK (B_SZ * NCHUNK)     // 512 chunk-blocks

typedef __attribute__((ext_vector_type(8))) short short8;
typedef __attribute__((ext_vector_type(4))) float f32x4;
typedef unsigned int uint;
typedef unsigned short ushort;

static __device__ __forceinline__ short f2bf(float f) {
  union { float f; uint u; } v; v.f = f;
  uint r = v.u + 0x7FFFu + ((v.u >> 16) & 1u);  // round-to-nearest-even
  return (short)(r >> 16);
}
static __device__ __forceinline__ float bf2f(uint h) {
  union { uint u; float f; } v; v.u = h << 16;
  return v.f;
}
static __device__ __forceinline__ uint pack2(float a, float b) {
  return (uint)(ushort)f2bf(a) | ((uint)(ushort)f2bf(b) << 16);
}

// ---------------------------------------------------------------------------
// k0_setup: R7/R9 VERBATIM (validated).
// ---------------------------------------------------------------------------
__global__ __launch_bounds__(256) void k0_setup(
    const float* __restrict__ nu_log, const float* __restrict__ theta_log,
    const float* __restrict__ gamma_log,
    const float* __restrict__ B_re, const float* __restrict__ B_im,
    const float* __restrict__ C_re, const float* __restrict__ C_im,
    const float* __restrict__ Dm,
    short* __restrict__ Wf1, short* __restrict__ Wf2,
    float2* __restrict__ lampow2) {
  int blk = blockIdx.x;
  if (blk < 320) {
    int idx = blk * 256 + threadIdx.x;
    if (idx < 16 * 512 * 8) {
      int j = idx & 7, col = (idx >> 3) & 511, kg = idx >> 12;
      int k = kg * 8 + j;
      int n = col >> 1, ri = col & 1;
      float g = expf(gamma_log[n]);
      float v = g * (ri ? B_im[n * D_IN + k] : B_re[n * D_IN + k]);
      Wf1[idx] = f2bf(v);
    }
    if (idx < 80 * 128 * 8) {
      int j = idx & 7, d = (idx >> 3) & 127, kg = idx >> 10;
      int k = kg * 8 + j;
      float v;
      if (k < 512) {
        int n = k >> 1;
        v = (k & 1) ? -C_im[d * N_ST + n] : C_re[d * N_ST + n];
      } else {
        v = Dm[d * D_IN + (k - 512)];
      }
      Wf2[idx] = f2bf(v);
    }
  } else {
    int j = blk - 320;  // 0..64
    int n = threadIdx.x;
    float e_nu = expf(nu_log[n]);
    float phase = expf(theta_log[n]);
    float r = expf(-(float)j * e_nu);
    float a = (float)j * phase;
    float2 v; v.x = r * cosf(a); v.y = r * sinf(a);
    lampow2[j * N_ST + n] = v;
  }
}

// ---------------------------------------------------------------------------
// kA: R2/R7/R9 VERBATIM (validated). Fused GEMM1 (bf16 MFMA) + local chunk
// scan -> global bf16 states + chunk carry E.
// ---------------------------------------------------------------------------
__global__ __launch_bounds__(256, 2) void kA(
    const float* __restrict__ x, const short* __restrict__ Wf1,
    const float2* __restrict__ lampow2,
    uint* __restrict__ states, float2* __restrict__ E) {
  __shared__ short bu[64 * 520];   // row-major, +8 pad per row

  int bc = blockIdx.x;
  size_t row0 = (size_t)bc * CHUNK;
  int tid = threadIdx.x;
  int lane = tid & 63, w = tid >> 6;
  int m = lane & 15, q = lane >> 4;

  f32x4 acc[32];
#pragma unroll
  for (int ct = 0; ct < 32; ++ct) acc[ct] = (f32x4){0.f, 0.f, 0.f, 0.f};

  const float* xrow = x + (row0 + 16 * w + m) * D_IN;

  for (int ks = 0; ks < 4; ++ks) {
    float4 xa = *(const float4*)(xrow + 32 * ks + 8 * q);
    float4 xb = *(const float4*)(xrow + 32 * ks + 8 * q + 4);
    short8 af;
    af[0] = f2bf(xa.x); af[1] = f2bf(xa.y); af[2] = f2bf(xa.z); af[3] = f2bf(xa.w);
    af[4] = f2bf(xb.x); af[5] = f2bf(xb.y); af[6] = f2bf(xb.z); af[7] = f2bf(xb.w);
    const short* wbase = Wf1 + ((size_t)(4 * ks + q) * 512 + m) * 8;
#pragma unroll
    for (int ct = 0; ct < 32; ++ct) {
      short8 bf = *(const short8*)(wbase + 16 * ct * 8);
      acc[ct] = __builtin_amdgcn_mfma_f32_16x16x32_bf16(af, bf, acc[ct], 0, 0, 0);
    }
  }

  // write Bu tile to LDS (bf16). C-layout: row=4q+r, col=m within 16x16 tile.
#pragma unroll
  for (int ct = 0; ct < 32; ++ct) {
#pragma unroll
    for (int r = 0; r < 4; ++r) {
      bu[(16 * w + 4 * q + r) * 520 + 16 * ct + m] = f2bf(acc[ct][r]);
    }
  }
  __syncthreads();

  // scan: thread n owns state n
  int n = tid;
  float2 lam = lampow2[N_ST + n];  // lam^1
  float sre = 0.f, sim = 0.f;
  uint* sg = states + row0 * N_ST + n;
  for (int j = 0; j < CHUNK; ++j) {
    uint p = ((const uint*)(bu + j * 520))[n];
    float br = bf2f(p & 0xffffu), bi = bf2f(p >> 16);
    float nr = fmaf(lam.x, sre, fmaf(-lam.y, sim, br));
    float ni = fmaf(lam.x, sim, fmaf(lam.y, sre, bi));
    sre = nr; sim = ni;
    sg[(size_t)j * N_ST] = pack2(sre, sim);
  }
  float2 e; e.x = sre; e.y = sim;
  E[bc * N_ST + n] = e;
}

// ---------------------------------------------------------------------------
// kC: R10's vectorized pipeline, occupancy-repaired: NO Pl array (LDS back to
// exactly 80 KB -> 2 blocks/CU). Each phase-1a' thread (n4=tid&63,
// rblk=tid>>6) computes the 4 carry chains it consumes (n=4n4..4n4+3) with
// the bit-identical R9 recurrence; E rows loaded as float4 pairs; 4
// independent chains give 4-way ILP. Then uint4 states fix-up -> b128 LDS
// store (R10-validated addressing), x -> As (R9 verbatim), MFMA (R9 verbatim).
// ---------------------------------------------------------------------------
__global__ __launch_bounds__(256, 2) void kC(
    const float* __restrict__ x, const uint* __restrict__ states,
    const float2* __restrict__ E, const float2* __restrict__ lampow2,
    const short* __restrict__ Wf2, float* __restrict__ y) {
  __shared__ short As[64 * 640];   // exactly 80 KB (nothing else)

  int bc = blockIdx.x;
  size_t row0 = (size_t)bc * CHUNK;
  int tid = threadIdx.x;
  int n4 = tid & 63, rblk = tid >> 6;

  // ---- carry chains for n = 4*n4+0..3 (bit-identical R9 recurrence) ----
  float2 p0, p1, p2, p3;
  p0.x = 0.f; p0.y = 0.f; p1.x = 0.f; p1.y = 0.f;
  p2.x = 0.f; p2.y = 0.f; p3.x = 0.f; p3.y = 0.f;
  {
    float4 lA = *(const float4*)(lampow2 + (size_t)CHUNK * N_ST + 4 * n4);
    float4 lB = *(const float4*)(lampow2 + (size_t)CHUNK * N_ST + 4 * n4 + 2);
    int c = bc & (NCHUNK - 1), b = bc >> 6;
    for (int j = 0; j < c; ++j) {
      const float2* eb = E + (size_t)((b << 6) + j) * N_ST + 4 * n4;
      float4 e01 = *(const float4*)eb;
      float4 e23 = *(const float4*)(eb + 2);
      float t;
      t    = fmaf(lA.x, p0.x, fmaf(-lA.y, p0.y, e01.x));
      p0.y = fmaf(lA.x, p0.y, fmaf( lA.y, p0.x, e01.y)); p0.x = t;
      t    = fmaf(lA.z, p1.x, fmaf(-lA.w, p1.y, e01.z));
      p1.y = fmaf(lA.z, p1.y, fmaf( lA.w, p1.x, e01.w)); p1.x = t;
      t    = fmaf(lB.x, p2.x, fmaf(-lB.y, p2.y, e23.x));
      p2.y = fmaf(lB.x, p2.y, fmaf( lB.y, p2.x, e23.y)); p2.x = t;
      t    = fmaf(lB.z, p3.x, fmaf(-lB.w, p3.y, e23.z));
      p3.y = fmaf(lB.z, p3.y, fmaf( lB.w, p3.x, e23.w)); p3.x = t;
    }
  }

  // phase 1b: x -> LDS bf16 (cols 512..639) (R9 verbatim; disjoint As cols)
  {
    int kxp = tid & 63, r0 = tid >> 6;
    int k = 512 + 2 * kxp;
    int g = k >> 3, koff = k & 7;
    for (int rr = 0; rr < 16; ++rr) {
      int row = r0 * 16 + rr;
      float2 xv = *(const float2*)(x + (row0 + row) * D_IN + 2 * kxp);
      int gp = (g & ~7) | ((g + row) & 7);
      *(uint*)(As + row * 640 + gp * 8 + koff) = pack2(xv.x, xv.y);
    }
  }

  // phase 1a': vectorized states fix-up -> As cols 0..511 (R10 addressing)
  {
#pragma unroll
    for (int rr = 0; rr < 16; ++rr) {
      int row = rblk * 16 + rr;
      uint4 sp = *(const uint4*)(states + ((row0 + row) * N_ST + 4 * n4));
      float4 lpa = *(const float4*)(lampow2 + ((size_t)(row + 1) * N_ST + 4 * n4));
      float4 lpb = *(const float4*)(lampow2 + ((size_t)(row + 1) * N_ST + 4 * n4 + 2));
      uint4 outv;
      {
        float sr = bf2f(sp.x & 0xffffu) + lpa.x * p0.x - lpa.y * p0.y;
        float si = bf2f(sp.x >> 16)     + lpa.x * p0.y + lpa.y * p0.x;
        outv.x = pack2(sr, si);
      }
      {
        float sr = bf2f(sp.y & 0xffffu) + lpa.z * p1.x - lpa.w * p1.y;
        float si = bf2f(sp.y >> 16)     + lpa.z * p1.y + lpa.w * p1.x;
        outv.y = pack2(sr, si);
      }
      {
        float sr = bf2f(sp.z & 0xffffu) + lpb.x * p2.x - lpb.y * p2.y;
        float si = bf2f(sp.z >> 16)     + lpb.x * p2.y + lpb.y * p2.x;
        outv.z = pack2(sr, si);
      }
      {
        float sr = bf2f(sp.w & 0xffffu) + lpb.z * p3.x - lpb.w * p3.y;
        float si = bf2f(sp.w >> 16)     + lpb.z * p3.y + lpb.w * p3.x;
        outv.w = pack2(sr, si);
      }
      int g = n4;
      int gp = (g & ~7) | ((g + row) & 7);
      *(uint4*)(As + row * 640 + gp * 8) = outv;
    }
  }
  __syncthreads();

  // phase 2: MFMA (R9 verbatim). wave w -> rows 16w..16w+15; 8 col-tiles.
  int lane = tid & 63, w = tid >> 6;
  int m = lane & 15, q = lane >> 4;
  int arow = 16 * w + m;

  f32x4 acc[8];
#pragma unroll
  for (int ct = 0; ct < 8; ++ct) acc[ct] = (f32x4){0.f, 0.f, 0.f, 0.f};

  for (int ks = 0; ks < 20; ++ks) {
    int g = 4 * ks + q;
    int gp = (g & ~7) | ((g + arow) & 7);
    short8 af = *(const short8*)(As + arow * 640 + gp * 8);
    const short* wbase = Wf2 + ((size_t)g * 128 + m) * 8;
#pragma unroll
    for (int ct = 0; ct < 8; ++ct) {
      short8 bf = *(const short8*)(wbase + 16 * ct * 8);
      acc[ct] = __builtin_amdgcn_mfma_f32_16x16x32_bf16(af, bf, acc[ct], 0, 0, 0);
    }
  }

#pragma unroll
  for (int ct = 0; ct < 8; ++ct) {
#pragma unroll
    for (int r = 0; r < 4; ++r) {
      y[(row0 + 16 * w + 4 * q + r) * D_OUT + 16 * ct + m] = acc[ct][r];
    }
  }
}

// ---------------------------------------------------------------------------
extern "C" void kernel_launch(void* const* d_in, const int* in_sizes, int n_in,
                              void* d_out, int out_size, void* d_ws, size_t ws_size,
                              hipStream_t stream) {
  const float* x         = (const float*)d_in[0];
  const float* nu_log    = (const float*)d_in[1];
  const float* theta_log = (const float*)d_in[2];
  const float* gamma_log = (const float*)d_in[3];
  const float* B_re      = (const float*)d_in[4];
  const float* B_im      = (const float*)d_in[5];
  const float* C_re      = (const float*)d_in[6];
  const float* C_im      = (const float*)d_in[7];
  const float* Dm        = (const float*)d_in[8];
  float* y = (float*)d_out;

  char* wp = (char*)d_ws;
  float2* lampow2 = (float2*)wp; wp += (size_t)(CHUNK + 1) * N_ST * sizeof(float2);
  short*  Wf1     = (short*)wp;  wp += (size_t)16 * 512 * 8 * sizeof(short);
  short*  Wf2     = (short*)wp;  wp += (size_t)80 * 128 * 8 * sizeof(short);
  float2* E       = (float2*)wp; wp += (size_t)NBLK * N_ST * sizeof(float2);
  uint*   states  = (uint*)wp;   wp += (size_t)BT * N_ST * sizeof(uint);

  hipLaunchKernelGGL(k0_setup, dim3(385), dim3(256), 0, stream,
                     nu_log, theta_log, gamma_log, B_re, B_im, C_re, C_im, Dm,
                     Wf1, Wf2, lampow2);
  hipLaunchKernelGGL(kA, dim3(NBLK), dim3(256), 0, stream,
                     x, Wf1, lampow2, states, E);
  hipLaunchKernelGGL(kC, dim3(NBLK), dim3(256), 0, stream,
                     x, states, E, lampow2, Wf2, y);
}

// Round 12
// 135.368 us; speedup vs baseline: 1.1507x; 1.0508x over previous
//
#include <hip/hip_runtime.h>
#include <math.h>

// Sizes (fixed by the problem)
#define B_SZ 8
#define T_LEN 4096
#define D_IN 128
#define D_OUT 128
#define N_ST 256
#define BT (B_SZ * T_LEN)        // 32768
#define CHUNK 64                 // scan chunk length
#define NCHUNK (T_LEN / CHUNK)   // 64 chunks per sequence
#define NBLK (B_SZ * NCHUNK)     // 512 chunk-blocks

typedef __attribute__((ext_vector_type(8))) short short8;
typedef __attribute__((ext_vector_type(4))) float f32x4;
typedef unsigned int uint;
typedef unsigned short ushort;

static __device__ __forceinline__ short f2bf(float f) {
  union { float f; uint u; } v; v.f = f;
  uint r = v.u + 0x7FFFu + ((v.u >> 16) & 1u);  // round-to-nearest-even
  return (short)(r >> 16);
}
static __device__ __forceinline__ float bf2f(uint h) {
  union { uint u; float f; } v; v.u = h << 16;
  return v.f;
}
static __device__ __forceinline__ uint pack2(float a, float b) {
  return (uint)(ushort)f2bf(a) | ((uint)(ushort)f2bf(b) << 16);
}

// ---------------------------------------------------------------------------
// k0_setup: R7/R9 weight-pack + lampow (verbatim) + xbf conversion
// (R4's elementwise body: xbf[c] = f2bf(x_flat[c])).
//  blk<320: pack; blk in [320,385): lampow row; blk>=385: xbf.
// ---------------------------------------------------------------------------
__global__ __launch_bounds__(256) void k0_setup(
    const float* __restrict__ x,
    const float* __restrict__ nu_log, const float* __restrict__ theta_log,
    const float* __restrict__ gamma_log,
    const float* __restrict__ B_re, const float* __restrict__ B_im,
    const float* __restrict__ C_re, const float* __restrict__ C_im,
    const float* __restrict__ Dm,
    short* __restrict__ Wf1, short* __restrict__ Wf2,
    float2* __restrict__ lampow2, short* __restrict__ xbf) {
  int blk = blockIdx.x;
  if (blk < 320) {
    int idx = blk * 256 + threadIdx.x;
    if (idx < 16 * 512 * 8) {
      int j = idx & 7, col = (idx >> 3) & 511, kg = idx >> 12;
      int k = kg * 8 + j;
      int n = col >> 1, ri = col & 1;
      float g = expf(gamma_log[n]);
      float v = g * (ri ? B_im[n * D_IN + k] : B_re[n * D_IN + k]);
      Wf1[idx] = f2bf(v);
    }
    if (idx < 80 * 128 * 8) {
      int j = idx & 7, d = (idx >> 3) & 127, kg = idx >> 10;
      int k = kg * 8 + j;
      float v;
      if (k < 512) {
        int n = k >> 1;
        v = (k & 1) ? -C_im[d * N_ST + n] : C_re[d * N_ST + n];
      } else {
        v = Dm[d * D_IN + (k - 512)];
      }
      Wf2[idx] = f2bf(v);
    }
  } else if (blk < 385) {
    int j = blk - 320;  // 0..64
    int n = threadIdx.x;
    float e_nu = expf(nu_log[n]);
    float phase = expf(theta_log[n]);
    float r = expf(-(float)j * e_nu);
    float a = (float)j * phase;
    float2 v; v.x = r * cosf(a); v.y = r * sinf(a);
    lampow2[j * N_ST + n] = v;
  } else {
    size_t i = (size_t)(blk - 385) * 256 + threadIdx.x;  // < BT*D_IN/8
    const float4* x4 = (const float4*)x;
    float4 a = x4[2 * i], b = x4[2 * i + 1];
    uint4 u;
    u.x = pack2(a.x, a.y); u.y = pack2(a.z, a.w);
    u.z = pack2(b.x, b.y); u.w = pack2(b.z, b.w);
    ((uint4*)xbf)[i] = u;
  }
}

// ---------------------------------------------------------------------------
// kA: R11 kA with A-fragments loaded directly from xbf (value-identical to
// f2bf of the float loads). Everything else verbatim.
// ---------------------------------------------------------------------------
__global__ __launch_bounds__(256, 2) void kA(
    const short* __restrict__ xbf, const short* __restrict__ Wf1,
    const float2* __restrict__ lampow2,
    uint* __restrict__ states, float2* __restrict__ E) {
  __shared__ short bu[64 * 520];   // row-major, +8 pad per row

  int bc = blockIdx.x;
  size_t row0 = (size_t)bc * CHUNK;
  int tid = threadIdx.x;
  int lane = tid & 63, w = tid >> 6;
  int m = lane & 15, q = lane >> 4;

  f32x4 acc[32];
#pragma unroll
  for (int ct = 0; ct < 32; ++ct) acc[ct] = (f32x4){0.f, 0.f, 0.f, 0.f};

  const short* xrow = xbf + (row0 + 16 * w + m) * D_IN;

  for (int ks = 0; ks < 4; ++ks) {
    short8 af = *(const short8*)(xrow + 32 * ks + 8 * q);
    const short* wbase = Wf1 + ((size_t)(4 * ks + q) * 512 + m) * 8;
#pragma unroll
    for (int ct = 0; ct < 32; ++ct) {
      short8 bf = *(const short8*)(wbase + 16 * ct * 8);
      acc[ct] = __builtin_amdgcn_mfma_f32_16x16x32_bf16(af, bf, acc[ct], 0, 0, 0);
    }
  }

  // write Bu tile to LDS (bf16). C-layout: row=4q+r, col=m within 16x16 tile.
#pragma unroll
  for (int ct = 0; ct < 32; ++ct) {
#pragma unroll
    for (int r = 0; r < 4; ++r) {
      bu[(16 * w + 4 * q + r) * 520 + 16 * ct + m] = f2bf(acc[ct][r]);
    }
  }
  __syncthreads();

  // scan: thread n owns state n (R11 verbatim)
  int n = tid;
  float2 lam = lampow2[N_ST + n];  // lam^1
  float sre = 0.f, sim = 0.f;
  uint* sg = states + row0 * N_ST + n;
  for (int j = 0; j < CHUNK; ++j) {
    uint p = ((const uint*)(bu + j * 520))[n];
    float br = bf2f(p & 0xffffu), bi = bf2f(p >> 16);
    float nr = fmaf(lam.x, sre, fmaf(-lam.y, sim, br));
    float ni = fmaf(lam.x, sim, fmaf(lam.y, sre, bi));
    sre = nr; sim = ni;
    sg[(size_t)j * N_ST] = pack2(sre, sim);
  }
  float2 e; e.x = sre; e.y = sim;
  E[bc * N_ST + n] = e;
}

// ---------------------------------------------------------------------------
// kB: R7 VERBATIM (validated). Carry scan across chunks per (b,n) -> P.
// ---------------------------------------------------------------------------
__global__ __launch_bounds__(256) void kB(
    const float2* __restrict__ E, const float2* __restrict__ lampow2,
    float2* __restrict__ P) {
  int g = blockIdx.x * 256 + threadIdx.x;  // b*N + n
  int n = g & (N_ST - 1);
  int b = g >> 8;
  float2 lamL = lampow2[CHUNK * N_ST + n];
  float cre = 0.f, cim = 0.f;
  for (int c = 0; c < NCHUNK; ++c) {
    int i = (b * NCHUNK + c) * N_ST + n;
    float2 pv; pv.x = cre; pv.y = cim;
    P[i] = pv;
    float2 e = E[i];
    float nre = fmaf(lamL.x, cre, fmaf(-lamL.y, cim, e.x));
    float nim = fmaf(lamL.x, cim, fmaf(lamL.y, cre, e.y));
    cre = nre; cim = nim;
  }
}

// ---------------------------------------------------------------------------
// kC: R11's vectorized pipeline, row-split 64->32: As = 32x640 bf16 =
// 40960 B -> 4 blocks/CU. blk = chunk*2 + half; row0 = blk*32;
// chunk-local j = j0 + local row, j0 = 32*(blk&1). Carry from global P
// (kB-validated values). All swizzle formulas identical, keyed on local row.
// ---------------------------------------------------------------------------
__global__ __launch_bounds__(256, 4) void kC(
    const short* __restrict__ xbf, const uint* __restrict__ states,
    const float2* __restrict__ P, const float2* __restrict__ lampow2,
    const short* __restrict__ Wf2, float* __restrict__ y) {
  __shared__ short As[32 * 640];   // 40 KB exactly

  int blk = blockIdx.x;            // 0..1023
  int bc = blk >> 1;               // chunk id
  int j0 = (blk & 1) * 32;         // chunk-local row base
  size_t row0 = (size_t)blk * 32;  // global time row base
  int tid = threadIdx.x;
  int n4 = tid & 63, rblk = tid >> 6;

  // ---- P for states 4*n4..4*n4+3 (global, bit-identical kB values) ----
  float4 pA = *(const float4*)(P + (size_t)bc * N_ST + 4 * n4);      // p0,p1
  float4 pB = *(const float4*)(P + (size_t)bc * N_ST + 4 * n4 + 2);  // p2,p3

  // phase 1b: x -> LDS bf16 (cols 512..639), uint copy from xbf
  {
    int kxp = tid & 63, r0 = tid >> 6;
    int k = 512 + 2 * kxp;
    int g = k >> 3, koff = k & 7;
    for (int rr = 0; rr < 8; ++rr) {
      int row = r0 * 8 + rr;       // local row 0..31
      uint xv = *(const uint*)(xbf + (row0 + row) * D_IN + 2 * kxp);
      int gp = (g & ~7) | ((g + row) & 7);
      *(uint*)(As + row * 640 + gp * 8 + koff) = xv;
    }
  }

  // phase 1a': vectorized states fix-up -> As cols 0..511
  {
#pragma unroll
    for (int rr = 0; rr < 8; ++rr) {
      int row = rblk * 8 + rr;     // local row 0..31
      int j = j0 + row;            // chunk-local time
      uint4 sp = *(const uint4*)(states + ((row0 + row) * N_ST + 4 * n4));
      float4 lpa = *(const float4*)(lampow2 + ((size_t)(j + 1) * N_ST + 4 * n4));
      float4 lpb = *(const float4*)(lampow2 + ((size_t)(j + 1) * N_ST + 4 * n4 + 2));
      uint4 outv;
      {
        float sr = bf2f(sp.x & 0xffffu) + lpa.x * pA.x - lpa.y * pA.y;
        float si = bf2f(sp.x >> 16)     + lpa.x * pA.y + lpa.y * pA.x;
        outv.x = pack2(sr, si);
      }
      {
        float sr = bf2f(sp.y & 0xffffu) + lpa.z * pA.z - lpa.w * pA.w;
        float si = bf2f(sp.y >> 16)     + lpa.z * pA.w + lpa.w * pA.z;
        outv.y = pack2(sr, si);
      }
      {
        float sr = bf2f(sp.z & 0xffffu) + lpb.x * pB.x - lpb.y * pB.y;
        float si = bf2f(sp.z >> 16)     + lpb.x * pB.y + lpb.y * pB.x;
        outv.z = pack2(sr, si);
      }
      {
        float sr = bf2f(sp.w & 0xffffu) + lpb.z * pB.z - lpb.w * pB.w;
        float si = bf2f(sp.w >> 16)     + lpb.z * pB.w + lpb.w * pB.z;
        outv.w = pack2(sr, si);
      }
      int g = n4;
      int gp = (g & ~7) | ((g + row) & 7);
      *(uint4*)(As + row * 640 + gp * 8) = outv;
    }
  }
  __syncthreads();

  // phase 2: MFMA. wave w -> row-tile (w&1), col-half (w>>1).
  int lane = tid & 63, w = tid >> 6;
  int m = lane & 15, q = lane >> 4;
  int rw = w & 1, ch = w >> 1;
  int arow = 16 * rw + m;          // local row

  f32x4 acc[4];
#pragma unroll
  for (int ct = 0; ct < 4; ++ct) acc[ct] = (f32x4){0.f, 0.f, 0.f, 0.f};

  for (int ks = 0; ks < 20; ++ks) {
    int g = 4 * ks + q;
    int gp = (g & ~7) | ((g + arow) & 7);
    short8 af = *(const short8*)(As + arow * 640 + gp * 8);
    const short* wbase = Wf2 + ((size_t)g * 128 + m) * 8;
#pragma unroll
    for (int ct = 0; ct < 4; ++ct) {
      int ctg = 4 * ch + ct;
      short8 bf = *(const short8*)(wbase + 16 * ctg * 8);
      acc[ct] = __builtin_amdgcn_mfma_f32_16x16x32_bf16(af, bf, acc[ct], 0, 0, 0);
    }
  }

#pragma unroll
  for (int ct = 0; ct < 4; ++ct) {
    int ctg = 4 * ch + ct;
#pragma unroll
    for (int r = 0; r < 4; ++r) {
      y[(row0 + 16 * rw + 4 * q + r) * D_OUT + 16 * ctg + m] = acc[ct][r];
    }
  }
}

// ---------------------------------------------------------------------------
extern "C" void kernel_launch(void* const* d_in, const int* in_sizes, int n_in,
                              void* d_out, int out_size, void* d_ws, size_t ws_size,
                              hipStream_t stream) {
  const float* x         = (const float*)d_in[0];
  const float* nu_log    = (const float*)d_in[1];
  const float* theta_log = (const float*)d_in[2];
  const float* gamma_log = (const float*)d_in[3];
  const float* B_re      = (const float*)d_in[4];
  const float* B_im      = (const float*)d_in[5];
  const float* C_re      = (const float*)d_in[6];
  const float* C_im      = (const float*)d_in[7];
  const float* Dm        = (const float*)d_in[8];
  float* y = (float*)d_out;

  char* wp = (char*)d_ws;
  float2* lampow2 = (float2*)wp; wp += (size_t)(CHUNK + 1) * N_ST * sizeof(float2);
  short*  Wf1     = (short*)wp;  wp += (size_t)16 * 512 * 8 * sizeof(short);
  short*  Wf2     = (short*)wp;  wp += (size_t)80 * 128 * 8 * sizeof(short);
  float2* E       = (float2*)wp; wp += (size_t)NBLK * N_ST * sizeof(float2);
  float2* P       = (float2*)wp; wp += (size_t)NBLK * N_ST * sizeof(float2);
  short*  xbf     = (short*)wp;  wp += (size_t)BT * D_IN * sizeof(short);
  uint*   states  = (uint*)wp;   wp += (size_t)BT * N_ST * sizeof(uint);

  hipLaunchKernelGGL(k0_setup, dim3(385 + BT * D_IN / 8 / 256), dim3(256), 0, stream,
                     x, nu_log, theta_log, gamma_log, B_re, B_im, C_re, C_im,
                     Dm, Wf1, Wf2, lampow2, xbf);
  hipLaunchKernelGGL(kA, dim3(NBLK), dim3(256), 0, stream,
                     xbf, Wf1, lampow2, states, E);
  hipLaunchKernelGGL(kB, dim3(B_SZ * N_ST / 256), dim3(256), 0, stream,
                     E, lampow2, P);
  hipLaunchKernelGGL(kC, dim3(2 * NBLK), dim3(256), 0, stream,
                     xbf, states, P, lampow2, Wf2, y);
}

// Round 16
// 133.380 us; speedup vs baseline: 1.1678x; 1.0149x over previous
//
#include <hip/hip_runtime.h>
#include <math.h>

// Sizes (fixed by the problem)
#define B_SZ 8
#define T_LEN 4096
#define D_IN 128
#define D_OUT 128
#define N_ST 256
#define BT (B_SZ * T_LEN)        // 32768
#define CHUNK 64                 // scan chunk length
#define NCHUNK (T_LEN / CHUNK)   // 64 chunks per sequence
#define NBLK (B_SZ * NCHUNK)     // 512 chunk-blocks

typedef __attribute__((ext_vector_type(8))) short short8;
typedef __attribute__((ext_vector_type(4))) float f32x4;
typedef unsigned int uint;
typedef unsigned short ushort;

static __device__ __forceinline__ short f2bf(float f) {
  union { float f; uint u; } v; v.f = f;
  uint r = v.u + 0x7FFFu + ((v.u >> 16) & 1u);  // round-to-nearest-even
  return (short)(r >> 16);
}
static __device__ __forceinline__ float bf2f(uint h) {
  union { uint u; float f; } v; v.u = h << 16;
  return v.f;
}
static __device__ __forceinline__ uint pack2(float a, float b) {
  return (uint)(ushort)f2bf(a) | ((uint)(ushort)f2bf(b) << 16);
}

// ---------------------------------------------------------------------------
// k0_setup: R12 VERBATIM. blk<320: weight pack; [320,385): lampow row;
// >=385: xbf conversion.
// ---------------------------------------------------------------------------
__global__ __launch_bounds__(256) void k0_setup(
    const float* __restrict__ x,
    const float* __restrict__ nu_log, const float* __restrict__ theta_log,
    const float* __restrict__ gamma_log,
    const float* __restrict__ B_re, const float* __restrict__ B_im,
    const float* __restrict__ C_re, const float* __restrict__ C_im,
    const float* __restrict__ Dm,
    short* __restrict__ Wf1, short* __restrict__ Wf2,
    float2* __restrict__ lampow2, short* __restrict__ xbf) {
  int blk = blockIdx.x;
  if (blk < 320) {
    int idx = blk * 256 + threadIdx.x;
    if (idx < 16 * 512 * 8) {
      int j = idx & 7, col = (idx >> 3) & 511, kg = idx >> 12;
      int k = kg * 8 + j;
      int n = col >> 1, ri = col & 1;
      float g = expf(gamma_log[n]);
      float v = g * (ri ? B_im[n * D_IN + k] : B_re[n * D_IN + k]);
      Wf1[idx] = f2bf(v);
    }
    if (idx < 80 * 128 * 8) {
      int j = idx & 7, d = (idx >> 3) & 127, kg = idx >> 10;
      int k = kg * 8 + j;
      float v;
      if (k < 512) {
        int n = k >> 1;
        v = (k & 1) ? -C_im[d * N_ST + n] : C_re[d * N_ST + n];
      } else {
        v = Dm[d * D_IN + (k - 512)];
      }
      Wf2[idx] = f2bf(v);
    }
  } else if (blk < 385) {
    int j = blk - 320;  // 0..64
    int n = threadIdx.x;
    float e_nu = expf(nu_log[n]);
    float phase = expf(theta_log[n]);
    float r = expf(-(float)j * e_nu);
    float a = (float)j * phase;
    float2 v; v.x = r * cosf(a); v.y = r * sinf(a);
    lampow2[j * N_ST + n] = v;
  } else {
    size_t i = (size_t)(blk - 385) * 256 + threadIdx.x;  // < BT*D_IN/8
    const float4* x4 = (const float4*)x;
    float4 a = x4[2 * i], b = x4[2 * i + 1];
    uint4 u;
    u.x = pack2(a.x, a.y); u.y = pack2(a.z, a.w);
    u.z = pack2(b.x, b.y); u.w = pack2(b.z, b.w);
    ((uint4*)xbf)[i] = u;
  }
}

// ---------------------------------------------------------------------------
// kA: R12 VERBATIM. Fused GEMM1 (bf16 MFMA, A-frags from xbf) + local chunk
// scan -> global bf16 states + chunk carry E. bu = 64x520 shorts, 2 blk/CU.
// NOTE: every retiling of this kernel (R13 time-split, R14/R15 state-split,
// even with provably bit-identical values) failed with schedule-varying
// absmax — do not modify this kernel's structure.
// ---------------------------------------------------------------------------
__global__ __launch_bounds__(256, 2) void kA(
    const short* __restrict__ xbf, const short* __restrict__ Wf1,
    const float2* __restrict__ lampow2,
    uint* __restrict__ states, float2* __restrict__ E) {
  __shared__ short bu[64 * 520];   // row-major, +8 pad per row

  int bc = blockIdx.x;
  size_t row0 = (size_t)bc * CHUNK;
  int tid = threadIdx.x;
  int lane = tid & 63, w = tid >> 6;
  int m = lane & 15, q = lane >> 4;

  f32x4 acc[32];
#pragma unroll
  for (int ct = 0; ct < 32; ++ct) acc[ct] = (f32x4){0.f, 0.f, 0.f, 0.f};

  const short* xrow = xbf + (row0 + 16 * w + m) * D_IN;

  for (int ks = 0; ks < 4; ++ks) {
    short8 af = *(const short8*)(xrow + 32 * ks + 8 * q);
    const short* wbase = Wf1 + ((size_t)(4 * ks + q) * 512 + m) * 8;
#pragma unroll
    for (int ct = 0; ct < 32; ++ct) {
      short8 bf = *(const short8*)(wbase + 16 * ct * 8);
      acc[ct] = __builtin_amdgcn_mfma_f32_16x16x32_bf16(af, bf, acc[ct], 0, 0, 0);
    }
  }

  // write Bu tile to LDS (bf16). C-layout: row=4q+r, col=m within 16x16 tile.
#pragma unroll
  for (int ct = 0; ct < 32; ++ct) {
#pragma unroll
    for (int r = 0; r < 4; ++r) {
      bu[(16 * w + 4 * q + r) * 520 + 16 * ct + m] = f2bf(acc[ct][r]);
    }
  }
  __syncthreads();

  // scan: thread n owns state n
  int n = tid;
  float2 lam = lampow2[N_ST + n];  // lam^1
  float sre = 0.f, sim = 0.f;
  uint* sg = states + row0 * N_ST + n;
  for (int j = 0; j < CHUNK; ++j) {
    uint p = ((const uint*)(bu + j * 520))[n];
    float br = bf2f(p & 0xffffu), bi = bf2f(p >> 16);
    float nr = fmaf(lam.x, sre, fmaf(-lam.y, sim, br));
    float ni = fmaf(lam.x, sim, fmaf(lam.y, sre, bi));
    sre = nr; sim = ni;
    sg[(size_t)j * N_ST] = pack2(sre, sim);
  }
  float2 e; e.x = sre; e.y = sim;
  E[bc * N_ST + n] = e;
}

// ---------------------------------------------------------------------------
// kB: R7/R12 VERBATIM. Carry scan across chunks per (b,n) -> P.
// ---------------------------------------------------------------------------
__global__ __launch_bounds__(256) void kB(
    const float2* __restrict__ E, const float2* __restrict__ lampow2,
    float2* __restrict__ P) {
  int g = blockIdx.x * 256 + threadIdx.x;  // b*N + n
  int n = g & (N_ST - 1);
  int b = g >> 8;
  float2 lamL = lampow2[CHUNK * N_ST + n];
  float cre = 0.f, cim = 0.f;
  for (int c = 0; c < NCHUNK; ++c) {
    int i = (b * NCHUNK + c) * N_ST + n;
    float2 pv; pv.x = cre; pv.y = cim;
    P[i] = pv;
    float2 e = E[i];
    float nre = fmaf(lamL.x, cre, fmaf(-lamL.y, cim, e.x));
    float nim = fmaf(lamL.x, cim, fmaf(lamL.y, cre, e.y));
    cre = nre; cim = nim;
  }
}

// ---------------------------------------------------------------------------
// kC: R12 VERBATIM. Row-split 64->32: As = 32x640 bf16 = 40 KB -> 4 blk/CU.
// blk = chunk*2 + half; vectorized states fix-up; carry from global P;
// GEMM2 (K=640) -> y.
// ---------------------------------------------------------------------------
__global__ __launch_bounds__(256, 4) void kC(
    const short* __restrict__ xbf, const uint* __restrict__ states,
    const float2* __restrict__ P, const float2* __restrict__ lampow2,
    const short* __restrict__ Wf2, float* __restrict__ y) {
  __shared__ short As[32 * 640];   // 40 KB exactly

  int blk = blockIdx.x;            // 0..1023
  int bc = blk >> 1;               // chunk id
  int j0 = (blk & 1) * 32;         // chunk-local row base
  size_t row0 = (size_t)blk * 32;  // global time row base
  int tid = threadIdx.x;
  int n4 = tid & 63, rblk = tid >> 6;

  // ---- P for states 4*n4..4*n4+3 (global, bit-identical kB values) ----
  float4 pA = *(const float4*)(P + (size_t)bc * N_ST + 4 * n4);      // p0,p1
  float4 pB = *(const float4*)(P + (size_t)bc * N_ST + 4 * n4 + 2);  // p2,p3

  // phase 1b: x -> LDS bf16 (cols 512..639), uint copy from xbf
  {
    int kxp = tid & 63, r0 = tid >> 6;
    int k = 512 + 2 * kxp;
    int g = k >> 3, koff = k & 7;
    for (int rr = 0; rr < 8; ++rr) {
      int row = r0 * 8 + rr;       // local row 0..31
      uint xv = *(const uint*)(xbf + (row0 + row) * D_IN + 2 * kxp);
      int gp = (g & ~7) | ((g + row) & 7);
      *(uint*)(As + row * 640 + gp * 8 + koff) = xv;
    }
  }

  // phase 1a': vectorized states fix-up -> As cols 0..511
  {
#pragma unroll
    for (int rr = 0; rr < 8; ++rr) {
      int row = rblk * 8 + rr;     // local row 0..31
      int j = j0 + row;            // chunk-local time
      uint4 sp = *(const uint4*)(states + ((row0 + row) * N_ST + 4 * n4));
      float4 lpa = *(const float4*)(lampow2 + ((size_t)(j + 1) * N_ST + 4 * n4));
      float4 lpb = *(const float4*)(lampow2 + ((size_t)(j + 1) * N_ST + 4 * n4 + 2));
      uint4 outv;
      {
        float sr = bf2f(sp.x & 0xffffu) + lpa.x * pA.x - lpa.y * pA.y;
        float si = bf2f(sp.x >> 16)     + lpa.x * pA.y + lpa.y * pA.x;
        outv.x = pack2(sr, si);
      }
      {
        float sr = bf2f(sp.y & 0xffffu) + lpa.z * pA.z - lpa.w * pA.w;
        float si = bf2f(sp.y >> 16)     + lpa.z * pA.w + lpa.w * pA.z;
        outv.y = pack2(sr, si);
      }
      {
        float sr = bf2f(sp.z & 0xffffu) + lpb.x * pB.x - lpb.y * pB.y;
        float si = bf2f(sp.z >> 16)     + lpb.x * pB.y + lpb.y * pB.x;
        outv.z = pack2(sr, si);
      }
      {
        float sr = bf2f(sp.w & 0xffffu) + lpb.z * pB.z - lpb.w * pB.w;
        float si = bf2f(sp.w >> 16)     + lpb.z * pB.w + lpb.w * pB.z;
        outv.w = pack2(sr, si);
      }
      int g = n4;
      int gp = (g & ~7) | ((g + row) & 7);
      *(uint4*)(As + row * 640 + gp * 8) = outv;
    }
  }
  __syncthreads();

  // phase 2: MFMA. wave w -> row-tile (w&1), col-half (w>>1).
  int lane = tid & 63, w = tid >> 6;
  int m = lane & 15, q = lane >> 4;
  int rw = w & 1, ch = w >> 1;
  int arow = 16 * rw + m;          // local row

  f32x4 acc[4];
#pragma unroll
  for (int ct = 0; ct < 4; ++ct) acc[ct] = (f32x4){0.f, 0.f, 0.f, 0.f};

  for (int ks = 0; ks < 20; ++ks) {
    int g = 4 * ks + q;
    int gp = (g & ~7) | ((g + arow) & 7);
    short8 af = *(const short8*)(As + arow * 640 + gp * 8);
    const short* wbase = Wf2 + ((size_t)g * 128 + m) * 8;
#pragma unroll
    for (int ct = 0; ct < 4; ++ct) {
      int ctg = 4 * ch + ct;
      short8 bf = *(const short8*)(wbase + 16 * ctg * 8);
      acc[ct] = __builtin_amdgcn_mfma_f32_16x16x32_bf16(af, bf, acc[ct], 0, 0, 0);
    }
  }

#pragma unroll
  for (int ct = 0; ct < 4; ++ct) {
    int ctg = 4 * ch + ct;
#pragma unroll
    for (int r = 0; r < 4; ++r) {
      y[(row0 + 16 * rw + 4 * q + r) * D_OUT + 16 * ctg + m] = acc[ct][r];
    }
  }
}

// ---------------------------------------------------------------------------
extern "C" void kernel_launch(void* const* d_in, const int* in_sizes, int n_in,
                              void* d_out, int out_size, void* d_ws, size_t ws_size,
                              hipStream_t stream) {
  const float* x         = (const float*)d_in[0];
  const float* nu_log    = (const float*)d_in[1];
  const float* theta_log = (const float*)d_in[2];
  const float* gamma_log = (const float*)d_in[3];
  const float* B_re      = (const float*)d_in[4];
  const float* B_im      = (const float*)d_in[5];
  const float* C_re      = (const float*)d_in[6];
  const float* C_im      = (const float*)d_in[7];
  const float* Dm        = (const float*)d_in[8];
  float* y = (float*)d_out;

  char* wp = (char*)d_ws;
  float2* lampow2 = (float2*)wp; wp += (size_t)(CHUNK + 1) * N_ST * sizeof(float2);
  short*  Wf1     = (short*)wp;  wp += (size_t)16 * 512 * 8 * sizeof(short);
  short*  Wf2     = (short*)wp;  wp += (size_t)80 * 128 * 8 * sizeof(short);
  float2* E       = (float2*)wp; wp += (size_t)NBLK * N_ST * sizeof(float2);
  float2* P       = (float2*)wp; wp += (size_t)NBLK * N_ST * sizeof(float2);
  short*  xbf     = (short*)wp;  wp += (size_t)BT * D_IN * sizeof(short);
  uint*   states  = (uint*)wp;   wp += (size_t)BT * N_ST * sizeof(uint);

  hipLaunchKernelGGL(k0_setup, dim3(385 + BT * D_IN / 8 / 256), dim3(256), 0, stream,
                     x, nu_log, theta_log, gamma_log, B_re, B_im, C_re, C_im,
                     Dm, Wf1, Wf2, lampow2, xbf);
  hipLaunchKernelGGL(kA, dim3(NBLK), dim3(256), 0, stream,
                     xbf, Wf1, lampow2, states, E);
  hipLaunchKernelGGL(kB, dim3(B_SZ * N_ST / 256), dim3(256), 0, stream,
                     E, lampow2, P);
  hipLaunchKernelGGL(kC, dim3(2 * NBLK), dim3(256), 0, stream,
                     xbf, states, P, lampow2, Wf2, y);
}